// Round 2
// baseline (137.551 us; speedup 1.0000x reference)
//
#include <hip/hip_runtime.h>

#define TPB    256
#define SLICE  512
#define MAXB   8
#define UNROLL 8

static inline int cdiv(int a, int b) { return (a + b - 1) / b; }

// Each lane owns TWO output points (coords in regs); block stages a 512-point
// input slice into LDS as float4. Hot loop: 8 input points unrolled, 16 d2
// values computed branchlessly, one fmin-tree any-hit test gates the rare
// count/gather body. Cross-slice combine: plain per-slice partials (no
// atomics, no memset) when ws_size permits, else atomic fallback.
__global__ void __launch_bounds__(TPB) ball_pool_main(
    const float* __restrict__ x,        // [B, n_in]
    const float* __restrict__ inp_pos,  // [n_in, 3]
    const float* __restrict__ out_pos,  // [n_out, 3]
    float* __restrict__ ws,
    int B, int n_in, int n_out, float r2, int partials)
{
    __shared__ float4 pts[SLICE];

    const int s = blockIdx.y;
    const int slice_base = s * SLICE;
    const int n = min(SLICE, n_in - slice_base);

    for (int j = (int)threadIdx.x; j < SLICE; j += TPB) {
        if (j < n) {
            const int g = slice_base + j;
            pts[j] = make_float4(inp_pos[3 * g], inp_pos[3 * g + 1],
                                 inp_pos[3 * g + 2], 0.0f);
        } else {
            pts[j] = make_float4(1e9f, 1e9f, 1e9f, 0.0f);  // sentinel: never hits
        }
    }
    __syncthreads();

    const int o0 = blockIdx.x * (2 * TPB) + (int)threadIdx.x;
    const int o1 = o0 + TPB;

    float oxa = 1e9f, oya = 1e9f, oza = 1e9f;
    float oxb = 1e9f, oyb = 1e9f, ozb = 1e9f;
    if (o0 < n_out) { oxa = out_pos[3*o0]; oya = out_pos[3*o0+1]; oza = out_pos[3*o0+2]; }
    if (o1 < n_out) { oxb = out_pos[3*o1]; oyb = out_pos[3*o1+1]; ozb = out_pos[3*o1+2]; }

    float cnta = 0.0f, cntb = 0.0f;
    float sa[MAXB], sb[MAXB];
#pragma unroll
    for (int b = 0; b < MAXB; ++b) { sa[b] = 0.0f; sb[b] = 0.0f; }

    for (int j = 0; j < SLICE; j += UNROLL) {
        float d2a[UNROLL], d2b[UNROLL];
#pragma unroll
        for (int u = 0; u < UNROLL; ++u) {
            const float4 p = pts[j + u];
            const float dxa = oxa - p.x, dya = oya - p.y, dza = oza - p.z;
            d2a[u] = dxa * dxa + dya * dya + dza * dza;
            const float dxb = oxb - p.x, dyb = oyb - p.y, dzb = ozb - p.z;
            d2b[u] = dxb * dxb + dyb * dyb + dzb * dzb;
        }
        // Per-lane any-hit over all 16 pairs via min-tree (7+8 v_min vs 16 cmps)
        float m = d2a[0];
#pragma unroll
        for (int u = 1; u < UNROLL; ++u) m = fminf(m, d2a[u]);
#pragma unroll
        for (int u = 0; u < UNROLL; ++u) m = fminf(m, d2b[u]);

        if (m <= r2) {  // wave takes this ~40% of groups; per-pair work inside is rare
#pragma unroll
            for (int u = 0; u < UNROLL; ++u) {
                const int gi = slice_base + j + u;
                if (d2a[u] <= r2) {
                    cnta += 1.0f;
#pragma unroll
                    for (int b = 0; b < MAXB; ++b)
                        if (b < B) sa[b] += x[b * n_in + gi];
                }
                if (d2b[u] <= r2) {
                    cntb += 1.0f;
#pragma unroll
                    for (int b = 0; b < MAXB; ++b)
                        if (b < B) sb[b] += x[b * n_in + gi];
                }
            }
        }
    }

    if (partials) {
        // psum[S][B][n_out] then pcnt[S][n_out]
        float* psum = ws;
        float* pcnt = ws + (size_t)gridDim.y * B * n_out;
        const size_t so = (size_t)s * B * n_out;
        if (o0 < n_out) {
            pcnt[(size_t)s * n_out + o0] = cnta;
#pragma unroll
            for (int b = 0; b < MAXB; ++b)
                if (b < B) psum[so + (size_t)b * n_out + o0] = sa[b];
        }
        if (o1 < n_out) {
            pcnt[(size_t)s * n_out + o1] = cntb;
#pragma unroll
            for (int b = 0; b < MAXB; ++b)
                if (b < B) psum[so + (size_t)b * n_out + o1] = sb[b];
        }
    } else {
        float* cnt = ws;            // [n_out]
        float* sum = ws + n_out;    // [B][n_out]
        if (o0 < n_out) {
            unsafeAtomicAdd(cnt + o0, cnta);
#pragma unroll
            for (int b = 0; b < MAXB; ++b)
                if (b < B) unsafeAtomicAdd(sum + (size_t)b * n_out + o0, sa[b]);
        }
        if (o1 < n_out) {
            unsafeAtomicAdd(cnt + o1, cntb);
#pragma unroll
            for (int b = 0; b < MAXB; ++b)
                if (b < B) unsafeAtomicAdd(sum + (size_t)b * n_out + o1, sb[b]);
        }
    }
}

__global__ void __launch_bounds__(TPB) final_atomic(
    const float* __restrict__ ws, float* __restrict__ out, int B, int n_out)
{
    const int i = blockIdx.x * TPB + (int)threadIdx.x;
    if (i >= B * n_out) return;
    const float c = ws[i % n_out];
    out[i] = ws[n_out + i] / (c > 0.0f ? c : 1.0f);
}

__global__ void __launch_bounds__(TPB) final_partials(
    const float* __restrict__ ws, float* __restrict__ out, int B, int n_out, int S)
{
    const int i = blockIdx.x * TPB + (int)threadIdx.x;
    if (i >= B * n_out) return;
    const int o = i % n_out;
    const float* psum = ws;
    const float* pcnt = ws + (size_t)S * B * n_out;
    float acc = 0.0f, c = 0.0f;
    for (int k = 0; k < S; ++k) {
        acc += psum[(size_t)k * B * n_out + i];
        c   += pcnt[(size_t)k * n_out + o];
    }
    out[i] = acc / (c > 0.0f ? c : 1.0f);
}

extern "C" void kernel_launch(void* const* d_in, const int* in_sizes, int n_in_args,
                              void* d_out, int out_size, void* d_ws, size_t ws_size,
                              hipStream_t stream) {
    const float* x  = (const float*)d_in[0];
    const float* ip = (const float*)d_in[1];
    const float* op = (const float*)d_in[2];
    float* out = (float*)d_out;

    const int n_in  = in_sizes[1] / 3;
    const int n_out = in_sizes[2] / 3;
    const int B     = in_sizes[0] / n_in;

    const int S = cdiv(n_in, SLICE);
    const size_t need_partials = (size_t)S * (B + 1) * n_out * sizeof(float);
    const int partials = (ws_size >= need_partials) ? 1 : 0;

    const float r2 = (float)(0.05 * 0.05);

    if (!partials) {
        hipMemsetAsync(d_ws, 0, (size_t)(B + 1) * n_out * sizeof(float), stream);
    }

    dim3 grid(cdiv(n_out, 2 * TPB), S);
    ball_pool_main<<<grid, TPB, 0, stream>>>(x, ip, op, (float*)d_ws,
                                             B, n_in, n_out, r2, partials);

    const int tot = B * n_out;
    if (partials) {
        final_partials<<<cdiv(tot, TPB), TPB, 0, stream>>>((const float*)d_ws, out,
                                                           B, n_out, S);
    } else {
        final_atomic<<<cdiv(tot, TPB), TPB, 0, stream>>>((const float*)d_ws, out,
                                                         B, n_out);
    }
}